// Round 12
// baseline (118.147 us; speedup 1.0000x reference)
//
#include <hip/hip_runtime.h>

// Problem constants (B=1 fixed by reference)
#define HW_TOTAL (480 * 640)           // 307200 pixels
#define NC 12                           // output channels (C-1)
#define VOX_TOTAL_C (240 * 144 * 240)   // 8,294,400 voxels (divisible by 32)

#define REC_STRIDE 16                   // floats per voxel record (64 B line)
#define NGROUPS (VOX_TOTAL_C / 4)       // 2,073,600 f32x4 groups per channel
#define NSTRIPS 162                     // strips per channel
#define GROUPS_PER_STRIP (NGROUPS / NSTRIPS)      // 12,800 (exact)
#define GROUPS_PER_WAVE  (GROUPS_PER_STRIP / 4)   // 3,200 (4 waves/block)
#define ITERS (GROUPS_PER_WAVE / 64)              // 50 iterations per wave

typedef float f32x4 __attribute__((ext_vector_type(4)));

// ---------------------------------------------------------------------------
// k1 (after 1 MB bitmap memset): scatter pixel records. REGULAR stores (R8
// lesson: NT scatter stores are 64 scattered partial-line writes per instr;
// regular stores let L2 merge the 4 16-B stores into one full dirty line).
// x reads pixel-indexed -> coalesced. bitmap bit via atomicOr (map values
// unique -> no rec conflicts; atomicOr commutative -> deterministic).
__global__ void scatter_rec_kernel(const float* __restrict__ x,
                                   const int* __restrict__ map,
                                   float* __restrict__ rec,
                                   unsigned int* __restrict__ bitmap) {
    int p = blockIdx.x * blockDim.x + threadIdx.x;
    if (p >= HW_TOTAL) return;
    int v = map[p];
    if (v <= 0) return;                 // invalid pixel (dropped)
    float vals[NC];
#pragma unroll
    for (int c = 0; c < NC; ++c)
        vals[c] = x[(size_t)(c + 1) * HW_TOTAL + p];
    f32x4* dst = (f32x4*)(rec + (size_t)v * REC_STRIDE);
    f32x4 a = {vals[0], vals[1], vals[2],  vals[3]};
    f32x4 b = {vals[4], vals[5], vals[6],  vals[7]};
    f32x4 c4 = {vals[8], vals[9], vals[10], vals[11]};
    f32x4 z = {0.f, 0.f, 0.f, 0.f};
    dst[0] = a; dst[1] = b; dst[2] = c4; dst[3] = z;   // full 64-B line
    atomicOr(&bitmap[v >> 5], 1u << (v & 31));
}

// ---------------------------------------------------------------------------
// k2: streaming gather, fill-kernel shape: ONE long contiguous NT stream per
// wave. Block b -> channel b%12, strip b/12; each of the block's 4 waves owns
// a contiguous 3200-group (51.2 KB) run of that channel and loops 50x:
// {coalesced bitmap word load, rare gated 4-B rec loads, one 1024-B NT
// store}. Shaping ladder so far (streams/wave x run length):
//   48x1: 147us | 12x1: 104 | 4x1: 96.2 | 4x4: 104.6 | 1x1-burst: 110.7
// This is the untested 1 x LONG cell = exactly the 6.8 TB/s fill pattern.
// 1944 blocks ~= device capacity; tiny VGPR -> 8 waves/SIMD hides gated-load
// latency. bitmap (1 MB) + touched rec lines (17.7 MB) fit L3 -> the 12
// channel-sweeps re-read them from L3, HBM-fetch once. Single unconditional
// NT store path (R5: no divergent stores; R7: NT, not regular -> L2 clean).
__global__ __launch_bounds__(256, 8)
void gather_rec_kernel(const float* __restrict__ rec,
                       const unsigned int* __restrict__ bitmap,
                       float* __restrict__ out) {
    const int b = blockIdx.x;
    const int c = b % NC;                              // channel 0..11
    const int strip = b / NC;                          // 0..161
    const int wave = threadIdx.x >> 6;
    const int lane = threadIdx.x & 63;
    int g = strip * GROUPS_PER_STRIP + wave * GROUPS_PER_WAVE + lane;
    const float* recc = rec + c;
    float* outc = out + (size_t)c * VOX_TOTAL_C;

    for (int i = 0; i < ITERS; ++i, g += 64) {
        unsigned int word = bitmap[g >> 3];            // 8 lanes share a word
        unsigned int nib = (word >> ((g & 7) * 4)) & 0xFu;
        size_t base = (size_t)g * 4;
        f32x4 o = {0.f, 0.f, 0.f, 0.f};
        if (nib) {                                     // rare: gated loads
            if (nib & 1u) o.x = recc[(base + 0) * REC_STRIDE];
            if (nib & 2u) o.y = recc[(base + 1) * REC_STRIDE];
            if (nib & 4u) o.z = recc[(base + 2) * REC_STRIDE];
            if (nib & 8u) o.w = recc[(base + 3) * REC_STRIDE];
        }
        // one 1024-B contiguous NT wave-store, advancing 1 KB/iter
        __builtin_nontemporal_store(o, (f32x4*)(outc + base));
    }
}

// ---------------------------------------------------------------------------
// Fallback (only if ws_size were too small): memset + naive scatter (R1 path).
__global__ void naive_scatter_kernel(const float* __restrict__ x,
                                     const int* __restrict__ map,
                                     float* __restrict__ out) {
    int p = blockIdx.x * blockDim.x + threadIdx.x;
    if (p >= HW_TOTAL) return;
    int v = map[p];
    if (v <= 0) return;
#pragma unroll
    for (int c = 0; c < NC; ++c)
        out[(size_t)c * VOX_TOTAL_C + (size_t)v] = x[(size_t)(c + 1) * HW_TOTAL + p];
}

extern "C" void kernel_launch(void* const* d_in, const int* in_sizes, int n_in,
                              void* d_out, int out_size, void* d_ws, size_t ws_size,
                              hipStream_t stream) {
    const float* x = (const float*)d_in[0];      // (1, 13, 480, 640) f32
    const int* map = (const int*)d_in[1];        // (1, 307200) i32
    float* out = (float*)d_out;                  // (1, 12, 240, 144, 240) f32

    const size_t rec_bytes = (size_t)VOX_TOTAL_C * REC_STRIDE * sizeof(float); // 531 MB
    const size_t bitmap_bytes = VOX_TOTAL_C / 8;                               // 1.04 MB

    if (ws_size < rec_bytes + bitmap_bytes) {
        // Safety net (ws is ~1.59 GB in this harness; shouldn't trigger).
        hipMemsetAsync(out, 0, (size_t)NC * VOX_TOTAL_C * sizeof(float), stream);
        naive_scatter_kernel<<<HW_TOTAL / 256, 256, 0, stream>>>(x, map, out);
        return;
    }

    float* rec = (float*)d_ws;
    unsigned int* bitmap = (unsigned int*)((char*)d_ws + rec_bytes);

    // Zero only the bitmap (1 MB) every call; rec is gated by bitmap bits.
    hipMemsetAsync(bitmap, 0, bitmap_bytes, stream);

    scatter_rec_kernel<<<HW_TOTAL / 256, 256, 0, stream>>>(x, map, rec, bitmap);

    // gather: 12 channels x 162 strips = 1944 blocks, 4 waves each
    gather_rec_kernel<<<NC * NSTRIPS, 256, 0, stream>>>(rec, bitmap, out);
}